// Round 1
// baseline (872.344 us; speedup 1.0000x reference)
//
#include <hip/hip_runtime.h>

typedef __attribute__((ext_vector_type(8))) short short8;
typedef __attribute__((ext_vector_type(4))) float f32x4;

#define EMB 768
#define SEQ 4096
#define NH 12
#define HD 64
// 8 * log2(e): folds the score scale AND the exp->exp2 conversion into Q
#define QSCALE 11.541560327111707f

__device__ inline ushort f2bf(float v) {
  union { float f; unsigned int u; } x; x.f = v;
  unsigned int r = x.u + 0x7fffu + ((x.u >> 16) & 1u);
  return (ushort)(r >> 16);
}
__device__ inline float bf2f(ushort u) {
  union { float f; unsigned int u32; } x; x.u32 = ((unsigned int)u) << 16;
  return x.f;
}

__global__ void split_k(const float* __restrict__ src, ushort* __restrict__ hi,
                        ushort* __restrict__ lo, int n) {
  int i = blockIdx.x * blockDim.x + threadIdx.x;
  if (i < n) {
    float v = src[i];
    ushort h = f2bf(v);
    hi[i] = h;
    lo[i] = f2bf(v - bf2f(h));
  }
}

// C[m,n] = sum_k A[m,k]*B[n,k]  (both K-contiguous, "bt" form), fp32-accurate via
// 3-term bf16 split MFMA. mode 0: C += bias -> Cout fp32. mode 1: scatter QKV.
__global__ __launch_bounds__(256) void gemm_bt_split(
    const ushort* __restrict__ Ah, const ushort* __restrict__ Al,
    const ushort* __restrict__ Bh, const ushort* __restrict__ Bl,
    int M, int N, int K, int mode,
    float* __restrict__ Cout, const float* __restrict__ bias,
    ushort* __restrict__ Qh, ushort* __restrict__ Ql,
    ushort* __restrict__ Kh, ushort* __restrict__ Kl,
    ushort* __restrict__ Vt) {
  // LDS tiles: 128 rows x 32 cols bf16, padded stride 40 (80B = 5x16B: b128-aligned,
  // 2-way bank aliasing only -> free per m136)
  __shared__ ushort sAh[128 * 40], sAl[128 * 40], sBh[128 * 40], sBl[128 * 40];

  const int tid = threadIdx.x;
  const int lane = tid & 63;
  const int w = tid >> 6;
  const int wm = w >> 1, wn = w & 1;
  const int col = lane & 15, quad = lane >> 4;
  const int bm = blockIdx.x, bn = blockIdx.y;

  // staging: thread covers row r, two 16B chunks
  const int r = tid >> 1;
  const int cb = (tid & 1) * 2;

  const ushort* gAh = Ah + (size_t)(bm * 128 + r) * K;
  const ushort* gAl = Al + (size_t)(bm * 128 + r) * K;
  const ushort* gBh = Bh + (size_t)(bn * 128 + r) * K;
  const ushort* gBl = Bl + (size_t)(bn * 128 + r) * K;

  f32x4 acc[4][4];
  const f32x4 zz = {0.f, 0.f, 0.f, 0.f};
#pragma unroll
  for (int i = 0; i < 4; ++i)
#pragma unroll
    for (int j = 0; j < 4; ++j) acc[i][j] = zz;

  for (int kt = 0; kt < K; kt += 32) {
    uint4 va[2], vb[2], vc[2], vd[2];
#pragma unroll
    for (int i = 0; i < 2; ++i) {
      int c8 = (cb + i) * 8;
      va[i] = *(const uint4*)(gAh + kt + c8);
      vb[i] = *(const uint4*)(gAl + kt + c8);
      vc[i] = *(const uint4*)(gBh + kt + c8);
      vd[i] = *(const uint4*)(gBl + kt + c8);
    }
    __syncthreads();
#pragma unroll
    for (int i = 0; i < 2; ++i) {
      int c8 = (cb + i) * 8;
      *(uint4*)(&sAh[r * 40 + c8]) = va[i];
      *(uint4*)(&sAl[r * 40 + c8]) = vb[i];
      *(uint4*)(&sBh[r * 40 + c8]) = vc[i];
      *(uint4*)(&sBl[r * 40 + c8]) = vd[i];
    }
    __syncthreads();

    short8 fah[4], fal[4], fbh[4], fbl[4];
#pragma unroll
    for (int t = 0; t < 4; ++t) {
      int ra = (wm * 64 + t * 16 + col) * 40 + quad * 8;
      fah[t] = *(const short8*)(&sAh[ra]);
      fal[t] = *(const short8*)(&sAl[ra]);
      int rb = (wn * 64 + t * 16 + col) * 40 + quad * 8;
      fbh[t] = *(const short8*)(&sBh[rb]);
      fbl[t] = *(const short8*)(&sBl[rb]);
    }
#pragma unroll
    for (int tm = 0; tm < 4; ++tm)
#pragma unroll
      for (int tn = 0; tn < 4; ++tn) {
        acc[tm][tn] = __builtin_amdgcn_mfma_f32_16x16x32_bf16(fah[tm], fbh[tn], acc[tm][tn], 0, 0, 0);
        acc[tm][tn] = __builtin_amdgcn_mfma_f32_16x16x32_bf16(fah[tm], fbl[tn], acc[tm][tn], 0, 0, 0);
        acc[tm][tn] = __builtin_amdgcn_mfma_f32_16x16x32_bf16(fal[tm], fbh[tn], acc[tm][tn], 0, 0, 0);
      }
  }

  const int m_base = bm * 128 + wm * 64;
  const int n_base = bn * 128 + wn * 64;

  if (mode == 0) {
#pragma unroll
    for (int tm = 0; tm < 4; ++tm)
#pragma unroll
      for (int tn = 0; tn < 4; ++tn) {
        int gn = n_base + tn * 16 + col;
        float b = bias[gn];
#pragma unroll
        for (int rr = 0; rr < 4; ++rr) {
          int gm = m_base + tm * 16 + quad * 4 + rr;
          Cout[(size_t)gm * N + gn] = acc[tm][tn][rr] + b;
        }
      }
  } else {
    int reg = bn / 6;  // 0:Q 1:K 2:V  (uniform per block)
#pragma unroll
    for (int tm = 0; tm < 4; ++tm)
#pragma unroll
      for (int tn = 0; tn < 4; ++tn) {
        int el = (bn % 6) * 128 + wn * 64 + tn * 16 + col;  // 0..767
        int hh = el >> 6, dd = el & 63;
#pragma unroll
        for (int rr = 0; rr < 4; ++rr) {
          int gm = m_base + tm * 16 + quad * 4 + rr;
          float v = acc[tm][tn][rr];
          if (reg == 0) {
            v *= QSCALE;
            ushort hi = f2bf(v);
            size_t idx = ((size_t)hh * SEQ + gm) * HD + dd;
            Qh[idx] = hi;
            Ql[idx] = f2bf(v - bf2f(hi));
          } else if (reg == 1) {
            ushort hi = f2bf(v);
            size_t idx = ((size_t)hh * SEQ + gm) * HD + dd;
            Kh[idx] = hi;
            Kl[idx] = f2bf(v - bf2f(hi));
          } else {
            Vt[((size_t)hh * HD + dd) * SEQ + gm] = f2bf(v);
          }
        }
      }
  }
}

// Flash attention: one head x 64 q-rows per block; 4 waves, each owns 16 q-rows
// independently (no block sync in the k-loop). Scores via 3-term split MFMA
// (Q pre-scaled by 8*log2e -> softmax in exp2 domain, exact).
__global__ __launch_bounds__(256) void attn_k(
    const ushort* __restrict__ Qh, const ushort* __restrict__ Ql,
    const ushort* __restrict__ Kh, const ushort* __restrict__ Kl,
    const ushort* __restrict__ Vt,
    ushort* __restrict__ Ch, ushort* __restrict__ Cl) {
  // per-wave private P tile: 16 rows x 64 cols bf16, stride 72 (144B = 9x16B aligned,
  // 2-way bank aliasing on b128 reads -> free)
  __shared__ ushort sP[4][16 * 72];

  const int tid = threadIdx.x, lane = tid & 63, w = tid >> 6;
  const int col = lane & 15, quad = lane >> 4;
  const int h = blockIdx.y;
  const int q0 = blockIdx.x * 64 + w * 16;

  const ushort* qh_base = Qh + ((size_t)h * SEQ + q0 + col) * HD;
  const ushort* ql_base = Ql + ((size_t)h * SEQ + q0 + col) * HD;
  short8 fqh[2], fql[2];
#pragma unroll
  for (int ks = 0; ks < 2; ++ks) {
    fqh[ks] = *(const short8*)(qh_base + ks * 32 + quad * 8);
    fql[ks] = *(const short8*)(ql_base + ks * 32 + quad * 8);
  }

  float m2[4], ell[4];
  f32x4 o[4];
  const f32x4 zz = {0.f, 0.f, 0.f, 0.f};
#pragma unroll
  for (int i = 0; i < 4; ++i) { m2[i] = -1e30f; ell[i] = 0.f; o[i] = zz; }

  const ushort* kh_head = Kh + (size_t)h * SEQ * HD;
  const ushort* kl_head = Kl + (size_t)h * SEQ * HD;
  const ushort* vt_head = Vt + (size_t)h * HD * SEQ;
  ushort* pw = &sP[w][0];

  for (int kb = 0; kb < SEQ; kb += 64) {
    f32x4 s[4];
#pragma unroll
    for (int tn = 0; tn < 4; ++tn) {
      const ushort* krh = kh_head + (size_t)(kb + tn * 16 + col) * HD;
      const ushort* krl = kl_head + (size_t)(kb + tn * 16 + col) * HD;
      f32x4 a = zz;
#pragma unroll
      for (int ks = 0; ks < 2; ++ks) {
        short8 fkh = *(const short8*)(krh + ks * 32 + quad * 8);
        short8 fkl = *(const short8*)(krl + ks * 32 + quad * 8);
        a = __builtin_amdgcn_mfma_f32_16x16x32_bf16(fqh[ks], fkh, a, 0, 0, 0);
        a = __builtin_amdgcn_mfma_f32_16x16x32_bf16(fqh[ks], fkl, a, 0, 0, 0);
        a = __builtin_amdgcn_mfma_f32_16x16x32_bf16(fql[ks], fkh, a, 0, 0, 0);
      }
      s[tn] = a;
    }
    // online softmax (exp2 domain), per 16-lane row-group reductions
    float vm[4];
#pragma unroll
    for (int rr = 0; rr < 4; ++rr)
      vm[rr] = fmaxf(fmaxf(s[0][rr], s[1][rr]), fmaxf(s[2][rr], s[3][rr]));
#pragma unroll
    for (int mk = 1; mk < 16; mk <<= 1)
#pragma unroll
      for (int rr = 0; rr < 4; ++rr) vm[rr] = fmaxf(vm[rr], __shfl_xor(vm[rr], mk, 64));

    float mn[4], alpha[4];
#pragma unroll
    for (int rr = 0; rr < 4; ++rr) {
      mn[rr] = fmaxf(m2[rr], vm[rr]);
      alpha[rr] = exp2f(m2[rr] - mn[rr]);
      m2[rr] = mn[rr];
      ell[rr] *= alpha[rr];
    }
#pragma unroll
    for (int td = 0; td < 4; ++td)
#pragma unroll
      for (int rr = 0; rr < 4; ++rr) o[td][rr] *= alpha[rr];

    float rs[4] = {0.f, 0.f, 0.f, 0.f};
#pragma unroll
    for (int tn = 0; tn < 4; ++tn)
#pragma unroll
      for (int rr = 0; rr < 4; ++rr) {
        float p = exp2f(s[tn][rr] - mn[rr]);
        rs[rr] += p;
        pw[(quad * 4 + rr) * 72 + tn * 16 + col] = f2bf(p);
      }
#pragma unroll
    for (int mk = 1; mk < 16; mk <<= 1)
#pragma unroll
      for (int rr = 0; rr < 4; ++rr) rs[rr] += __shfl_xor(rs[rr], mk, 64);
#pragma unroll
    for (int rr = 0; rr < 4; ++rr) ell[rr] += rs[rr];

    // drain this wave's LDS writes before reading back (wave-private region)
    asm volatile("s_waitcnt lgkmcnt(0)" ::: "memory");

    short8 fp[2];
#pragma unroll
    for (int ks = 0; ks < 2; ++ks)
      fp[ks] = *(const short8*)(pw + col * 72 + ks * 32 + quad * 8);

#pragma unroll
    for (int td = 0; td < 4; ++td) {
      const ushort* vrow = vt_head + (size_t)(td * 16 + col) * SEQ + kb;
#pragma unroll
      for (int ks = 0; ks < 2; ++ks) {
        short8 fv = *(const short8*)(vrow + ks * 32 + quad * 8);
        o[td] = __builtin_amdgcn_mfma_f32_16x16x32_bf16(fp[ks], fv, o[td], 0, 0, 0);
      }
    }
  }

  // epilogue: normalize, split to bf16 hi/lo ctx [4096][768]
#pragma unroll
  for (int td = 0; td < 4; ++td)
#pragma unroll
    for (int rr = 0; rr < 4; ++rr) {
      float v = o[td][rr] / ell[rr];
      int l = q0 + quad * 4 + rr;
      int d = h * 64 + td * 16 + col;
      ushort hi = f2bf(v);
      size_t idx = (size_t)l * EMB + d;
      Ch[idx] = hi;
      Cl[idx] = f2bf(v - bf2f(hi));
    }
}

extern "C" void kernel_launch(void* const* d_in, const int* in_sizes, int n_in,
                              void* d_out, int out_size, void* d_ws, size_t ws_size,
                              hipStream_t stream) {
  const float* x = (const float*)d_in[0];       // [4096][768]
  const float* qkv_w = (const float*)d_in[1];   // [2304][768]
  const float* out_w = (const float*)d_in[2];   // [768][768]
  const float* out_b = (const float*)d_in[3];   // [768]
  float* out = (float*)d_out;                   // [4096][768]

  char* p = (char*)d_ws;
  auto carve = [&](size_t bytes) {
    char* q = p;
    p += (bytes + 255) & ~(size_t)255;
    return q;
  };
  const size_t NX = (size_t)SEQ * EMB;       // 3,145,728
  const size_t NQW = (size_t)3 * EMB * EMB;  // 1,769,472
  const size_t NOW = (size_t)EMB * EMB;      // 589,824
  const size_t NQKV = (size_t)NH * SEQ * HD; // 3,145,728

  ushort* xh = (ushort*)carve(NX * 2);
  ushort* xl = (ushort*)carve(NX * 2);
  ushort* qwh = (ushort*)carve(NQW * 2);
  ushort* qwl = (ushort*)carve(NQW * 2);
  ushort* owh = (ushort*)carve(NOW * 2);
  ushort* owl = (ushort*)carve(NOW * 2);
  ushort* Qh = (ushort*)carve(NQKV * 2);
  ushort* Ql = (ushort*)carve(NQKV * 2);
  ushort* Kh = (ushort*)carve(NQKV * 2);
  ushort* Kl = (ushort*)carve(NQKV * 2);
  ushort* Vt = (ushort*)carve(NQKV * 2);
  ushort* Ch = (ushort*)carve(NX * 2);
  ushort* Cl = (ushort*)carve(NX * 2);

  split_k<<<dim3((int)(NX / 256)), 256, 0, stream>>>(x, xh, xl, (int)NX);
  split_k<<<dim3((int)(NQW / 256)), 256, 0, stream>>>(qkv_w, qwh, qwl, (int)NQW);
  split_k<<<dim3((int)(NOW / 256)), 256, 0, stream>>>(out_w, owh, owl, (int)NOW);

  // QKV: M=4096, N=2304, K=768 -> scatter epilogue
  gemm_bt_split<<<dim3(32, 18), 256, 0, stream>>>(
      xh, xl, qwh, qwl, SEQ, 3 * EMB, EMB, 1,
      nullptr, nullptr, Qh, Ql, Kh, Kl, Vt);

  attn_k<<<dim3(SEQ / 64, NH), 256, 0, stream>>>(Qh, Ql, Kh, Kl, Vt, Ch, Cl);

  // out proj: M=4096, N=768, K=768, + bias -> d_out
  gemm_bt_split<<<dim3(32, 6), 256, 0, stream>>>(
      Ch, Cl, owh, owl, SEQ, EMB, EMB, 0,
      out, out_b, nullptr, nullptr, nullptr, nullptr, nullptr);
}

// Round 2
// 871.930 us; speedup vs baseline: 1.0005x; 1.0005x over previous
//
#include <hip/hip_runtime.h>

typedef __attribute__((ext_vector_type(8))) short short8;
typedef __attribute__((ext_vector_type(4))) float f32x4;

#define EMB 768
#define SEQ 4096
#define NH 12
#define HD 64
// 8 * log2(e): folds the score scale AND the exp->exp2 conversion into Q
#define QSCALE 11.541560327111707f

__device__ inline ushort f2bf(float v) {
  union { float f; unsigned int u; } x; x.f = v;
  unsigned int r = x.u + 0x7fffu + ((x.u >> 16) & 1u);
  return (ushort)(r >> 16);
}
__device__ inline float bf2f(ushort u) {
  union { float f; unsigned int u32; } x; x.u32 = ((unsigned int)u) << 16;
  return x.f;
}

__global__ void split_k(const float* __restrict__ src, ushort* __restrict__ hi,
                        ushort* __restrict__ lo, int n) {
  int i = blockIdx.x * blockDim.x + threadIdx.x;
  if (i < n) {
    float v = src[i];
    ushort h = f2bf(v);
    hi[i] = h;
    lo[i] = f2bf(v - bf2f(h));
  }
}

// C[m,n] = sum_k A[m,k]*B[n,k]  (both K-contiguous, "bt" form), fp32-accurate via
// 3-term bf16 split MFMA. mode 0: C += bias -> Cout fp32. mode 1: scatter QKV.
__global__ __launch_bounds__(256) void gemm_bt_split(
    const ushort* __restrict__ Ah, const ushort* __restrict__ Al,
    const ushort* __restrict__ Bh, const ushort* __restrict__ Bl,
    int M, int N, int K, int mode,
    float* __restrict__ Cout, const float* __restrict__ bias,
    ushort* __restrict__ Qh, ushort* __restrict__ Ql,
    ushort* __restrict__ Kh, ushort* __restrict__ Kl,
    ushort* __restrict__ Vt) {
  // LDS tiles: 128 rows x 32 cols bf16, padded stride 40 (80B = 5x16B: b128-aligned,
  // 2-way bank aliasing only -> free per m136)
  __shared__ ushort sAh[128 * 40], sAl[128 * 40], sBh[128 * 40], sBl[128 * 40];

  const int tid = threadIdx.x;
  const int lane = tid & 63;
  const int w = tid >> 6;
  const int wm = w >> 1, wn = w & 1;
  const int col = lane & 15, quad = lane >> 4;
  const int bm = blockIdx.x, bn = blockIdx.y;

  // staging: thread covers row r, two 16B chunks
  const int r = tid >> 1;
  const int cb = (tid & 1) * 2;

  const ushort* gAh = Ah + (size_t)(bm * 128 + r) * K;
  const ushort* gAl = Al + (size_t)(bm * 128 + r) * K;
  const ushort* gBh = Bh + (size_t)(bn * 128 + r) * K;
  const ushort* gBl = Bl + (size_t)(bn * 128 + r) * K;

  f32x4 acc[4][4];
  const f32x4 zz = {0.f, 0.f, 0.f, 0.f};
#pragma unroll
  for (int i = 0; i < 4; ++i)
#pragma unroll
    for (int j = 0; j < 4; ++j) acc[i][j] = zz;

  for (int kt = 0; kt < K; kt += 32) {
    uint4 va[2], vb[2], vc[2], vd[2];
#pragma unroll
    for (int i = 0; i < 2; ++i) {
      int c8 = (cb + i) * 8;
      va[i] = *(const uint4*)(gAh + kt + c8);
      vb[i] = *(const uint4*)(gAl + kt + c8);
      vc[i] = *(const uint4*)(gBh + kt + c8);
      vd[i] = *(const uint4*)(gBl + kt + c8);
    }
    __syncthreads();
#pragma unroll
    for (int i = 0; i < 2; ++i) {
      int c8 = (cb + i) * 8;
      *(uint4*)(&sAh[r * 40 + c8]) = va[i];
      *(uint4*)(&sAl[r * 40 + c8]) = vb[i];
      *(uint4*)(&sBh[r * 40 + c8]) = vc[i];
      *(uint4*)(&sBl[r * 40 + c8]) = vd[i];
    }
    __syncthreads();

    short8 fah[4], fal[4], fbh[4], fbl[4];
#pragma unroll
    for (int t = 0; t < 4; ++t) {
      int ra = (wm * 64 + t * 16 + col) * 40 + quad * 8;
      fah[t] = *(const short8*)(&sAh[ra]);
      fal[t] = *(const short8*)(&sAl[ra]);
      int rb = (wn * 64 + t * 16 + col) * 40 + quad * 8;
      fbh[t] = *(const short8*)(&sBh[rb]);
      fbl[t] = *(const short8*)(&sBl[rb]);
    }
#pragma unroll
    for (int tm = 0; tm < 4; ++tm)
#pragma unroll
      for (int tn = 0; tn < 4; ++tn) {
        acc[tm][tn] = __builtin_amdgcn_mfma_f32_16x16x32_bf16(fah[tm], fbh[tn], acc[tm][tn], 0, 0, 0);
        acc[tm][tn] = __builtin_amdgcn_mfma_f32_16x16x32_bf16(fah[tm], fbl[tn], acc[tm][tn], 0, 0, 0);
        acc[tm][tn] = __builtin_amdgcn_mfma_f32_16x16x32_bf16(fal[tm], fbh[tn], acc[tm][tn], 0, 0, 0);
      }
  }

  const int m_base = bm * 128 + wm * 64;
  const int n_base = bn * 128 + wn * 64;

  if (mode == 0) {
#pragma unroll
    for (int tm = 0; tm < 4; ++tm)
#pragma unroll
      for (int tn = 0; tn < 4; ++tn) {
        int gn = n_base + tn * 16 + col;
        float b = bias[gn];
#pragma unroll
        for (int rr = 0; rr < 4; ++rr) {
          int gm = m_base + tm * 16 + quad * 4 + rr;
          Cout[(size_t)gm * N + gn] = acc[tm][tn][rr] + b;
        }
      }
  } else {
    int reg = bn / 6;  // 0:Q 1:K 2:V  (uniform per block)
#pragma unroll
    for (int tm = 0; tm < 4; ++tm)
#pragma unroll
      for (int tn = 0; tn < 4; ++tn) {
        int el = (bn % 6) * 128 + wn * 64 + tn * 16 + col;  // 0..767
        int hh = el >> 6, dd = el & 63;
#pragma unroll
        for (int rr = 0; rr < 4; ++rr) {
          int gm = m_base + tm * 16 + quad * 4 + rr;
          float v = acc[tm][tn][rr];
          if (reg == 0) {
            v *= QSCALE;
            ushort hi = f2bf(v);
            size_t idx = ((size_t)hh * SEQ + gm) * HD + dd;
            Qh[idx] = hi;
            Ql[idx] = f2bf(v - bf2f(hi));
          } else if (reg == 1) {
            ushort hi = f2bf(v);
            size_t idx = ((size_t)hh * SEQ + gm) * HD + dd;
            Kh[idx] = hi;
            Kl[idx] = f2bf(v - bf2f(hi));
          } else {
            Vt[((size_t)hh * HD + dd) * SEQ + gm] = f2bf(v);
          }
        }
      }
  }
}

// Flash attention: one head x 64 q-rows per block; 4 waves, each owns 16 q-rows
// independently (no block sync in the k-loop). Scores via 3-term split MFMA
// (Q pre-scaled by 8*log2e -> softmax in exp2 domain, exact).
// 128 keys per softmax update; __launch_bounds__(256,3): grid is 3 blocks/CU
// (768/256), so cap at 3 waves/SIMD -> ~170 VGPR budget so the 48 dwordx4
// loads per iter can stay in flight (R1: VGPR=64 serialized every load batch).
__global__ __launch_bounds__(256, 3) void attn_k(
    const ushort* __restrict__ Qh, const ushort* __restrict__ Ql,
    const ushort* __restrict__ Kh, const ushort* __restrict__ Kl,
    const ushort* __restrict__ Vt,
    ushort* __restrict__ Ch, ushort* __restrict__ Cl) {
  // per-wave private P tile: 16 rows x 128 cols bf16, stride 136 (272B = 17x16B
  // aligned; b128 reads see only 2-way bank aliasing -> free)
  __shared__ ushort sP[4][16 * 136];

  const int tid = threadIdx.x, lane = tid & 63, w = tid >> 6;
  const int col = lane & 15, quad = lane >> 4;
  const int h = blockIdx.y;
  const int q0 = blockIdx.x * 64 + w * 16;

  const ushort* qh_base = Qh + ((size_t)h * SEQ + q0 + col) * HD;
  const ushort* ql_base = Ql + ((size_t)h * SEQ + q0 + col) * HD;
  short8 fqh[2], fql[2];
#pragma unroll
  for (int ks = 0; ks < 2; ++ks) {
    fqh[ks] = *(const short8*)(qh_base + ks * 32 + quad * 8);
    fql[ks] = *(const short8*)(ql_base + ks * 32 + quad * 8);
  }

  float m2[4], ell[4];
  f32x4 o[4];
  const f32x4 zz = {0.f, 0.f, 0.f, 0.f};
#pragma unroll
  for (int i = 0; i < 4; ++i) { m2[i] = -1e30f; ell[i] = 0.f; o[i] = zz; }

  const ushort* kh_head = Kh + (size_t)h * SEQ * HD;
  const ushort* kl_head = Kl + (size_t)h * SEQ * HD;
  const ushort* vt_head = Vt + (size_t)h * HD * SEQ;
  ushort* pw = &sP[w][0];

  for (int kb = 0; kb < SEQ; kb += 128) {
    // ---- scores for 128 keys: 8 tiles of 16 ----
    f32x4 s[8];
#pragma unroll
    for (int tn = 0; tn < 8; ++tn) {
      const ushort* krh = kh_head + (size_t)(kb + tn * 16 + col) * HD;
      const ushort* krl = kl_head + (size_t)(kb + tn * 16 + col) * HD;
      f32x4 a = zz;
#pragma unroll
      for (int ks = 0; ks < 2; ++ks) {
        short8 fkh = *(const short8*)(krh + ks * 32 + quad * 8);
        short8 fkl = *(const short8*)(krl + ks * 32 + quad * 8);
        a = __builtin_amdgcn_mfma_f32_16x16x32_bf16(fqh[ks], fkh, a, 0, 0, 0);
        a = __builtin_amdgcn_mfma_f32_16x16x32_bf16(fqh[ks], fkl, a, 0, 0, 0);
        a = __builtin_amdgcn_mfma_f32_16x16x32_bf16(fql[ks], fkh, a, 0, 0, 0);
      }
      s[tn] = a;
    }
    // ---- online softmax (exp2 domain), one update per 128 keys ----
    float vm[4];
#pragma unroll
    for (int rr = 0; rr < 4; ++rr) {
      float a0 = fmaxf(fmaxf(s[0][rr], s[1][rr]), fmaxf(s[2][rr], s[3][rr]));
      float a1 = fmaxf(fmaxf(s[4][rr], s[5][rr]), fmaxf(s[6][rr], s[7][rr]));
      vm[rr] = fmaxf(a0, a1);
    }
#pragma unroll
    for (int mk = 1; mk < 16; mk <<= 1)
#pragma unroll
      for (int rr = 0; rr < 4; ++rr) vm[rr] = fmaxf(vm[rr], __shfl_xor(vm[rr], mk, 64));

    float mn[4], alpha[4];
#pragma unroll
    for (int rr = 0; rr < 4; ++rr) {
      mn[rr] = fmaxf(m2[rr], vm[rr]);
      alpha[rr] = exp2f(m2[rr] - mn[rr]);
      m2[rr] = mn[rr];
      ell[rr] *= alpha[rr];
    }
#pragma unroll
    for (int td = 0; td < 4; ++td)
#pragma unroll
      for (int rr = 0; rr < 4; ++rr) o[td][rr] *= alpha[rr];

    float rs[4] = {0.f, 0.f, 0.f, 0.f};
#pragma unroll
    for (int tn = 0; tn < 8; ++tn)
#pragma unroll
      for (int rr = 0; rr < 4; ++rr) {
        float p = exp2f(s[tn][rr] - mn[rr]);
        rs[rr] += p;
        pw[(quad * 4 + rr) * 136 + tn * 16 + col] = f2bf(p);
      }
#pragma unroll
    for (int mk = 1; mk < 16; mk <<= 1)
#pragma unroll
      for (int rr = 0; rr < 4; ++rr) rs[rr] += __shfl_xor(rs[rr], mk, 64);
#pragma unroll
    for (int rr = 0; rr < 4; ++rr) ell[rr] += rs[rr];

    // drain this wave's LDS writes before reading back (wave-private region)
    asm volatile("s_waitcnt lgkmcnt(0)" ::: "memory");

    short8 fp[4];
#pragma unroll
    for (int ks = 0; ks < 4; ++ks)
      fp[ks] = *(const short8*)(pw + col * 136 + ks * 32 + quad * 8);

#pragma unroll
    for (int td = 0; td < 4; ++td) {
      const ushort* vrow = vt_head + (size_t)(td * 16 + col) * SEQ + kb;
#pragma unroll
      for (int ks = 0; ks < 4; ++ks) {
        short8 fv = *(const short8*)(vrow + ks * 32 + quad * 8);
        o[td] = __builtin_amdgcn_mfma_f32_16x16x32_bf16(fp[ks], fv, o[td], 0, 0, 0);
      }
    }
  }

  // epilogue: normalize, split to bf16 hi/lo ctx [4096][768]
#pragma unroll
  for (int td = 0; td < 4; ++td)
#pragma unroll
    for (int rr = 0; rr < 4; ++rr) {
      float v = o[td][rr] / ell[rr];
      int l = q0 + quad * 4 + rr;
      int d = h * 64 + td * 16 + col;
      ushort hi = f2bf(v);
      size_t idx = (size_t)l * EMB + d;
      Ch[idx] = hi;
      Cl[idx] = f2bf(v - bf2f(hi));
    }
}

extern "C" void kernel_launch(void* const* d_in, const int* in_sizes, int n_in,
                              void* d_out, int out_size, void* d_ws, size_t ws_size,
                              hipStream_t stream) {
  const float* x = (const float*)d_in[0];       // [4096][768]
  const float* qkv_w = (const float*)d_in[1];   // [2304][768]
  const float* out_w = (const float*)d_in[2];   // [768][768]
  const float* out_b = (const float*)d_in[3];   // [768]
  float* out = (float*)d_out;                   // [4096][768]

  char* p = (char*)d_ws;
  auto carve = [&](size_t bytes) {
    char* q = p;
    p += (bytes + 255) & ~(size_t)255;
    return q;
  };
  const size_t NX = (size_t)SEQ * EMB;       // 3,145,728
  const size_t NQW = (size_t)3 * EMB * EMB;  // 1,769,472
  const size_t NOW = (size_t)EMB * EMB;      // 589,824
  const size_t NQKV = (size_t)NH * SEQ * HD; // 3,145,728

  ushort* xh = (ushort*)carve(NX * 2);
  ushort* xl = (ushort*)carve(NX * 2);
  ushort* qwh = (ushort*)carve(NQW * 2);
  ushort* qwl = (ushort*)carve(NQW * 2);
  ushort* owh = (ushort*)carve(NOW * 2);
  ushort* owl = (ushort*)carve(NOW * 2);
  ushort* Qh = (ushort*)carve(NQKV * 2);
  ushort* Ql = (ushort*)carve(NQKV * 2);
  ushort* Kh = (ushort*)carve(NQKV * 2);
  ushort* Kl = (ushort*)carve(NQKV * 2);
  ushort* Vt = (ushort*)carve(NQKV * 2);
  ushort* Ch = (ushort*)carve(NX * 2);
  ushort* Cl = (ushort*)carve(NX * 2);

  split_k<<<dim3((int)(NX / 256)), 256, 0, stream>>>(x, xh, xl, (int)NX);
  split_k<<<dim3((int)(NQW / 256)), 256, 0, stream>>>(qkv_w, qwh, qwl, (int)NQW);
  split_k<<<dim3((int)(NOW / 256)), 256, 0, stream>>>(out_w, owh, owl, (int)NOW);

  // QKV: M=4096, N=2304, K=768 -> scatter epilogue
  gemm_bt_split<<<dim3(32, 18), 256, 0, stream>>>(
      xh, xl, qwh, qwl, SEQ, 3 * EMB, EMB, 1,
      nullptr, nullptr, Qh, Ql, Kh, Kl, Vt);

  attn_k<<<dim3(SEQ / 64, NH), 256, 0, stream>>>(Qh, Ql, Kh, Kl, Vt, Ch, Cl);

  // out proj: M=4096, N=768, K=768, + bias -> d_out
  gemm_bt_split<<<dim3(32, 6), 256, 0, stream>>>(
      Ch, Cl, owh, owl, SEQ, EMB, EMB, 0,
      out, out_b, nullptr, nullptr, nullptr, nullptr, nullptr);
}

// Round 3
// 755.949 us; speedup vs baseline: 1.1540x; 1.1534x over previous
//
#include <hip/hip_runtime.h>

typedef __attribute__((ext_vector_type(8))) short short8;
typedef __attribute__((ext_vector_type(4))) float f32x4;

#define EMB 768
#define SEQ 4096
#define NH 12
#define HD 64
// 8 * log2(e): folds the score scale AND the exp->exp2 conversion into Q
#define QSCALE 11.541560327111707f

__device__ inline ushort f2bf(float v) {
  union { float f; unsigned int u; } x; x.f = v;
  unsigned int r = x.u + 0x7fffu + ((x.u >> 16) & 1u);
  return (ushort)(r >> 16);
}
__device__ inline float bf2f(ushort u) {
  union { float f; unsigned int u32; } x; x.u32 = ((unsigned int)u) << 16;
  return x.f;
}

__global__ void split_k(const float* __restrict__ src, ushort* __restrict__ hi,
                        ushort* __restrict__ lo, int n) {
  int i = blockIdx.x * blockDim.x + threadIdx.x;
  if (i < n) {
    float v = src[i];
    ushort h = f2bf(v);
    hi[i] = h;
    lo[i] = f2bf(v - bf2f(h));
  }
}

// C[m,n] = sum_k A[m,k]*B[n,k]  (both K-contiguous, "bt" form), fp32-accurate via
// 3-term bf16 split MFMA. mode 0: C += bias -> Cout fp32. mode 1: scatter QKV.
__global__ __launch_bounds__(256) void gemm_bt_split(
    const ushort* __restrict__ Ah, const ushort* __restrict__ Al,
    const ushort* __restrict__ Bh, const ushort* __restrict__ Bl,
    int M, int N, int K, int mode,
    float* __restrict__ Cout, const float* __restrict__ bias,
    ushort* __restrict__ Qh, ushort* __restrict__ Ql,
    ushort* __restrict__ Kh, ushort* __restrict__ Kl,
    ushort* __restrict__ Vt) {
  __shared__ ushort sAh[128 * 40], sAl[128 * 40], sBh[128 * 40], sBl[128 * 40];

  const int tid = threadIdx.x;
  const int lane = tid & 63;
  const int w = tid >> 6;
  const int wm = w >> 1, wn = w & 1;
  const int col = lane & 15, quad = lane >> 4;
  const int bm = blockIdx.x, bn = blockIdx.y;

  const int r = tid >> 1;
  const int cb = (tid & 1) * 2;

  const ushort* gAh = Ah + (size_t)(bm * 128 + r) * K;
  const ushort* gAl = Al + (size_t)(bm * 128 + r) * K;
  const ushort* gBh = Bh + (size_t)(bn * 128 + r) * K;
  const ushort* gBl = Bl + (size_t)(bn * 128 + r) * K;

  f32x4 acc[4][4];
  const f32x4 zz = {0.f, 0.f, 0.f, 0.f};
#pragma unroll
  for (int i = 0; i < 4; ++i)
#pragma unroll
    for (int j = 0; j < 4; ++j) acc[i][j] = zz;

  for (int kt = 0; kt < K; kt += 32) {
    uint4 va[2], vb[2], vc[2], vd[2];
#pragma unroll
    for (int i = 0; i < 2; ++i) {
      int c8 = (cb + i) * 8;
      va[i] = *(const uint4*)(gAh + kt + c8);
      vb[i] = *(const uint4*)(gAl + kt + c8);
      vc[i] = *(const uint4*)(gBh + kt + c8);
      vd[i] = *(const uint4*)(gBl + kt + c8);
    }
    __syncthreads();
#pragma unroll
    for (int i = 0; i < 2; ++i) {
      int c8 = (cb + i) * 8;
      *(uint4*)(&sAh[r * 40 + c8]) = va[i];
      *(uint4*)(&sAl[r * 40 + c8]) = vb[i];
      *(uint4*)(&sBh[r * 40 + c8]) = vc[i];
      *(uint4*)(&sBl[r * 40 + c8]) = vd[i];
    }
    __syncthreads();

    short8 fah[4], fal[4], fbh[4], fbl[4];
#pragma unroll
    for (int t = 0; t < 4; ++t) {
      int ra = (wm * 64 + t * 16 + col) * 40 + quad * 8;
      fah[t] = *(const short8*)(&sAh[ra]);
      fal[t] = *(const short8*)(&sAl[ra]);
      int rb = (wn * 64 + t * 16 + col) * 40 + quad * 8;
      fbh[t] = *(const short8*)(&sBh[rb]);
      fbl[t] = *(const short8*)(&sBl[rb]);
    }
#pragma unroll
    for (int tm = 0; tm < 4; ++tm)
#pragma unroll
      for (int tn = 0; tn < 4; ++tn) {
        acc[tm][tn] = __builtin_amdgcn_mfma_f32_16x16x32_bf16(fah[tm], fbh[tn], acc[tm][tn], 0, 0, 0);
        acc[tm][tn] = __builtin_amdgcn_mfma_f32_16x16x32_bf16(fah[tm], fbl[tn], acc[tm][tn], 0, 0, 0);
        acc[tm][tn] = __builtin_amdgcn_mfma_f32_16x16x32_bf16(fal[tm], fbh[tn], acc[tm][tn], 0, 0, 0);
      }
  }

  const int m_base = bm * 128 + wm * 64;
  const int n_base = bn * 128 + wn * 64;

  if (mode == 0) {
#pragma unroll
    for (int tm = 0; tm < 4; ++tm)
#pragma unroll
      for (int tn = 0; tn < 4; ++tn) {
        int gn = n_base + tn * 16 + col;
        float b = bias[gn];
#pragma unroll
        for (int rr = 0; rr < 4; ++rr) {
          int gm = m_base + tm * 16 + quad * 4 + rr;
          Cout[(size_t)gm * N + gn] = acc[tm][tn][rr] + b;
        }
      }
  } else {
    int reg = bn / 6;  // 0:Q 1:K 2:V  (uniform per block)
#pragma unroll
    for (int tm = 0; tm < 4; ++tm)
#pragma unroll
      for (int tn = 0; tn < 4; ++tn) {
        int el = (bn % 6) * 128 + wn * 64 + tn * 16 + col;  // 0..767
        int hh = el >> 6, dd = el & 63;
#pragma unroll
        for (int rr = 0; rr < 4; ++rr) {
          int gm = m_base + tm * 16 + quad * 4 + rr;
          float v = acc[tm][tn][rr];
          if (reg == 0) {
            v *= QSCALE;
            ushort hi = f2bf(v);
            size_t idx = ((size_t)hh * SEQ + gm) * HD + dd;
            Qh[idx] = hi;
            Ql[idx] = f2bf(v - bf2f(hi));
          } else if (reg == 1) {
            ushort hi = f2bf(v);
            size_t idx = ((size_t)hh * SEQ + gm) * HD + dd;
            Kh[idx] = hi;
            Kl[idx] = f2bf(v - bf2f(hi));
          } else {
            Vt[((size_t)hh * HD + dd) * SEQ + gm] = f2bf(v);
          }
        }
      }
  }
}

// Flash attention, R3 structure: cooperative LDS staging of K/V (shared by all
// 4 waves; R2 had each wave loading the full head -> 48 serial L2-latency loads
// per iter = 13.5k cyc/iter, 95% stall). Now: 12 batched dwordx4 loads/thread,
// prefetched one iteration ahead into registers -> latency hidden behind compute.
// LDS 70KB -> 2 blocks/CU.
__global__ __launch_bounds__(256, 2) void attn_k(
    const ushort* __restrict__ Qh, const ushort* __restrict__ Ql,
    const ushort* __restrict__ Kh, const ushort* __restrict__ Kl,
    const ushort* __restrict__ Vt,
    ushort* __restrict__ Ch, ushort* __restrict__ Cl) {
  // K tiles: 128 keys x 64 dims, stride 72 (144B = 9x16B -> b128 reads/writes at
  // conflict-free minimum). Vt tile: 64 dims x 128 keys, stride 136 (17x16B).
  __shared__ ushort sKh[128 * 72];
  __shared__ ushort sKl[128 * 72];
  __shared__ ushort sVt[64 * 136];
  // per-wave private P tile: 16 rows x 128 cols, stride 136
  __shared__ ushort sP[4][16 * 136];

  const int tid = threadIdx.x, lane = tid & 63, w = tid >> 6;
  const int col = lane & 15, quad = lane >> 4;
  const int h = blockIdx.y;
  const int q0 = blockIdx.x * 64 + w * 16;

  const ushort* qh_base = Qh + ((size_t)h * SEQ + q0 + col) * HD;
  const ushort* ql_base = Ql + ((size_t)h * SEQ + q0 + col) * HD;
  short8 fqh[2], fql[2];
#pragma unroll
  for (int ks = 0; ks < 2; ++ks) {
    fqh[ks] = *(const short8*)(qh_base + ks * 32 + quad * 8);
    fql[ks] = *(const short8*)(ql_base + ks * 32 + quad * 8);
  }

  float m2[4], ell[4];
  f32x4 o[4];
  const f32x4 zz = {0.f, 0.f, 0.f, 0.f};
#pragma unroll
  for (int i = 0; i < 4; ++i) { m2[i] = -1e30f; ell[i] = 0.f; o[i] = zz; }

  const ushort* khg = Kh + (size_t)h * SEQ * HD;  // [key][dim] -> +kb*64 linear
  const ushort* klg = Kl + (size_t)h * SEQ * HD;
  const ushort* vtg = Vt + (size_t)h * HD * SEQ;  // [dim][key]
  ushort* pw = &sP[w][0];

  // ---- staging prefetch registers (one iteration ahead) ----
  uint4 rkh[4], rkl[4], rvt[4];
#define PREFETCH(kb)                                                        \
  {                                                                         \
    _Pragma("unroll") for (int i = 0; i < 4; ++i) {                         \
      int ch = tid + i * 256;                                               \
      rkh[i] = *(const uint4*)(khg + (size_t)(kb)*64 + ch * 8);             \
      rkl[i] = *(const uint4*)(klg + (size_t)(kb)*64 + ch * 8);             \
      rvt[i] = *(const uint4*)(vtg + (size_t)(ch >> 4) * SEQ + (kb) + (ch & 15) * 8); \
    }                                                                       \
  }

  PREFETCH(0);

  for (int kb = 0; kb < SEQ; kb += 128) {
    __syncthreads();  // all waves done reading previous tile
#pragma unroll
    for (int i = 0; i < 4; ++i) {
      int ch = tid + i * 256;
      *(uint4*)(&sKh[(ch >> 3) * 72 + (ch & 7) * 8]) = rkh[i];
      *(uint4*)(&sKl[(ch >> 3) * 72 + (ch & 7) * 8]) = rkl[i];
      *(uint4*)(&sVt[(ch >> 4) * 136 + (ch & 15) * 8]) = rvt[i];
    }
    __syncthreads();
    if (kb + 128 < SEQ) PREFETCH(kb + 128);  // overlap with compute below

    // ---- scores for 128 keys: 8 tiles of 16, 3-term split MFMA ----
    f32x4 s[8];
#pragma unroll
    for (int tn = 0; tn < 8; ++tn) {
      f32x4 a = zz;
#pragma unroll
      for (int ks = 0; ks < 2; ++ks) {
        short8 fkh = *(const short8*)(&sKh[(tn * 16 + col) * 72 + ks * 32 + quad * 8]);
        short8 fkl = *(const short8*)(&sKl[(tn * 16 + col) * 72 + ks * 32 + quad * 8]);
        a = __builtin_amdgcn_mfma_f32_16x16x32_bf16(fqh[ks], fkh, a, 0, 0, 0);
        a = __builtin_amdgcn_mfma_f32_16x16x32_bf16(fqh[ks], fkl, a, 0, 0, 0);
        a = __builtin_amdgcn_mfma_f32_16x16x32_bf16(fql[ks], fkh, a, 0, 0, 0);
      }
      s[tn] = a;
    }

    // ---- online softmax (exp2 domain) ----
    float vm[4];
#pragma unroll
    for (int rr = 0; rr < 4; ++rr) {
      float a0 = fmaxf(fmaxf(s[0][rr], s[1][rr]), fmaxf(s[2][rr], s[3][rr]));
      float a1 = fmaxf(fmaxf(s[4][rr], s[5][rr]), fmaxf(s[6][rr], s[7][rr]));
      vm[rr] = fmaxf(a0, a1);
    }
#pragma unroll
    for (int mk = 1; mk < 16; mk <<= 1)
#pragma unroll
      for (int rr = 0; rr < 4; ++rr) vm[rr] = fmaxf(vm[rr], __shfl_xor(vm[rr], mk, 64));

    float mn[4], alpha[4];
#pragma unroll
    for (int rr = 0; rr < 4; ++rr) {
      mn[rr] = fmaxf(m2[rr], vm[rr]);
      alpha[rr] = exp2f(m2[rr] - mn[rr]);
      m2[rr] = mn[rr];
      ell[rr] *= alpha[rr];
    }
#pragma unroll
    for (int td = 0; td < 4; ++td)
#pragma unroll
      for (int rr = 0; rr < 4; ++rr) o[td][rr] *= alpha[rr];

    float rs[4] = {0.f, 0.f, 0.f, 0.f};
#pragma unroll
    for (int tn = 0; tn < 8; ++tn)
#pragma unroll
      for (int rr = 0; rr < 4; ++rr) {
        float p = exp2f(s[tn][rr] - mn[rr]);
        rs[rr] += p;
        pw[(quad * 4 + rr) * 136 + tn * 16 + col] = f2bf(p);
      }
#pragma unroll
    for (int mk = 1; mk < 16; mk <<= 1)
#pragma unroll
      for (int rr = 0; rr < 4; ++rr) rs[rr] += __shfl_xor(rs[rr], mk, 64);
#pragma unroll
    for (int rr = 0; rr < 4; ++rr) ell[rr] += rs[rr];

    // drain this wave's P writes before reading back (wave-private region)
    asm volatile("s_waitcnt lgkmcnt(0)" ::: "memory");

    short8 fp[4];
#pragma unroll
    for (int ks = 0; ks < 4; ++ks)
      fp[ks] = *(const short8*)(pw + col * 136 + ks * 32 + quad * 8);

#pragma unroll
    for (int td = 0; td < 4; ++td) {
#pragma unroll
      for (int ks = 0; ks < 4; ++ks) {
        short8 fv = *(const short8*)(&sVt[(td * 16 + col) * 136 + ks * 32 + quad * 8]);
        o[td] = __builtin_amdgcn_mfma_f32_16x16x32_bf16(fp[ks], fv, o[td], 0, 0, 0);
      }
    }
  }

  // epilogue: normalize, split to bf16 hi/lo ctx [4096][768]
#pragma unroll
  for (int td = 0; td < 4; ++td)
#pragma unroll
    for (int rr = 0; rr < 4; ++rr) {
      float v = o[td][rr] / ell[rr];
      int l = q0 + quad * 4 + rr;
      int d = h * 64 + td * 16 + col;
      ushort hi = f2bf(v);
      size_t idx = (size_t)l * EMB + d;
      Ch[idx] = hi;
      Cl[idx] = f2bf(v - bf2f(hi));
    }
}

extern "C" void kernel_launch(void* const* d_in, const int* in_sizes, int n_in,
                              void* d_out, int out_size, void* d_ws, size_t ws_size,
                              hipStream_t stream) {
  const float* x = (const float*)d_in[0];       // [4096][768]
  const float* qkv_w = (const float*)d_in[1];   // [2304][768]
  const float* out_w = (const float*)d_in[2];   // [768][768]
  const float* out_b = (const float*)d_in[3];   // [768]
  float* out = (float*)d_out;                   // [4096][768]

  char* p = (char*)d_ws;
  auto carve = [&](size_t bytes) {
    char* q = p;
    p += (bytes + 255) & ~(size_t)255;
    return q;
  };
  const size_t NX = (size_t)SEQ * EMB;       // 3,145,728
  const size_t NQW = (size_t)3 * EMB * EMB;  // 1,769,472
  const size_t NOW = (size_t)EMB * EMB;      // 589,824
  const size_t NQKV = (size_t)NH * SEQ * HD; // 3,145,728

  ushort* xh = (ushort*)carve(NX * 2);
  ushort* xl = (ushort*)carve(NX * 2);
  ushort* qwh = (ushort*)carve(NQW * 2);
  ushort* qwl = (ushort*)carve(NQW * 2);
  ushort* owh = (ushort*)carve(NOW * 2);
  ushort* owl = (ushort*)carve(NOW * 2);
  ushort* Qh = (ushort*)carve(NQKV * 2);
  ushort* Ql = (ushort*)carve(NQKV * 2);
  ushort* Kh = (ushort*)carve(NQKV * 2);
  ushort* Kl = (ushort*)carve(NQKV * 2);
  ushort* Vt = (ushort*)carve(NQKV * 2);
  ushort* Ch = (ushort*)carve(NX * 2);
  ushort* Cl = (ushort*)carve(NX * 2);

  split_k<<<dim3((int)(NX / 256)), 256, 0, stream>>>(x, xh, xl, (int)NX);
  split_k<<<dim3((int)(NQW / 256)), 256, 0, stream>>>(qkv_w, qwh, qwl, (int)NQW);
  split_k<<<dim3((int)(NOW / 256)), 256, 0, stream>>>(out_w, owh, owl, (int)NOW);

  // QKV: M=4096, N=2304, K=768 -> scatter epilogue
  gemm_bt_split<<<dim3(32, 18), 256, 0, stream>>>(
      xh, xl, qwh, qwl, SEQ, 3 * EMB, EMB, 1,
      nullptr, nullptr, Qh, Ql, Kh, Kl, Vt);

  attn_k<<<dim3(SEQ / 64, NH), 256, 0, stream>>>(Qh, Ql, Kh, Kl, Vt, Ch, Cl);

  // out proj: M=4096, N=768, K=768, + bias -> d_out
  gemm_bt_split<<<dim3(32, 6), 256, 0, stream>>>(
      Ch, Cl, owh, owl, SEQ, EMB, EMB, 0,
      out, out_b, nullptr, nullptr, nullptr, nullptr, nullptr);
}

// Round 4
// 566.875 us; speedup vs baseline: 1.5389x; 1.3335x over previous
//
#include <hip/hip_runtime.h>

typedef __attribute__((ext_vector_type(8))) short short8;
typedef __attribute__((ext_vector_type(4))) float f32x4;

#define EMB 768
#define SEQ 4096
#define NH 12
#define HD 64
// 8 * log2(e): folds the score scale AND the exp->exp2 conversion into Q
#define QSCALE 11.541560327111707f

#define GLOBAL_AS __attribute__((address_space(1)))
#define LDS_AS __attribute__((address_space(3)))

__device__ inline ushort f2bf(float v) {
  union { float f; unsigned int u; } x; x.f = v;
  unsigned int r = x.u + 0x7fffu + ((x.u >> 16) & 1u);
  return (ushort)(r >> 16);
}
__device__ inline float bf2f(ushort u) {
  union { float f; unsigned int u32; } x; x.u32 = ((unsigned int)u) << 16;
  return x.f;
}

__global__ void split_k(const float* __restrict__ src, ushort* __restrict__ hi,
                        ushort* __restrict__ lo, int n) {
  int i = blockIdx.x * blockDim.x + threadIdx.x;
  if (i < n) {
    float v = src[i];
    ushort h = f2bf(v);
    hi[i] = h;
    lo[i] = f2bf(v - bf2f(h));
  }
}

// C[m,n] = sum_k A[m,k]*B[n,k]  (both K-contiguous, "bt" form), fp32-accurate via
// 3-term bf16 split MFMA. mode 0: C += bias -> Cout fp32. mode 1: scatter QKV.
// K/V are stored XOR-chunk-swizzled (see attn_k) so attn's lane-ordered
// global_load_lds DMA yields a bank-conflict-free LDS image.
__global__ __launch_bounds__(256) void gemm_bt_split(
    const ushort* __restrict__ Ah, const ushort* __restrict__ Al,
    const ushort* __restrict__ Bh, const ushort* __restrict__ Bl,
    int M, int N, int K, int mode,
    float* __restrict__ Cout, const float* __restrict__ bias,
    ushort* __restrict__ Qh, ushort* __restrict__ Ql,
    ushort* __restrict__ Kh, ushort* __restrict__ Kl,
    ushort* __restrict__ Vt) {
  __shared__ ushort sAh[128 * 40], sAl[128 * 40], sBh[128 * 40], sBl[128 * 40];

  const int tid = threadIdx.x;
  const int lane = tid & 63;
  const int w = tid >> 6;
  const int wm = w >> 1, wn = w & 1;
  const int col = lane & 15, quad = lane >> 4;
  const int bm = blockIdx.x, bn = blockIdx.y;

  const int r = tid >> 1;
  const int cb = (tid & 1) * 2;

  const ushort* gAh = Ah + (size_t)(bm * 128 + r) * K;
  const ushort* gAl = Al + (size_t)(bm * 128 + r) * K;
  const ushort* gBh = Bh + (size_t)(bn * 128 + r) * K;
  const ushort* gBl = Bl + (size_t)(bn * 128 + r) * K;

  f32x4 acc[4][4];
  const f32x4 zz = {0.f, 0.f, 0.f, 0.f};
#pragma unroll
  for (int i = 0; i < 4; ++i)
#pragma unroll
    for (int j = 0; j < 4; ++j) acc[i][j] = zz;

  for (int kt = 0; kt < K; kt += 32) {
    uint4 va[2], vb[2], vc[2], vd[2];
#pragma unroll
    for (int i = 0; i < 2; ++i) {
      int c8 = (cb + i) * 8;
      va[i] = *(const uint4*)(gAh + kt + c8);
      vb[i] = *(const uint4*)(gAl + kt + c8);
      vc[i] = *(const uint4*)(gBh + kt + c8);
      vd[i] = *(const uint4*)(gBl + kt + c8);
    }
    __syncthreads();
#pragma unroll
    for (int i = 0; i < 2; ++i) {
      int c8 = (cb + i) * 8;
      *(uint4*)(&sAh[r * 40 + c8]) = va[i];
      *(uint4*)(&sAl[r * 40 + c8]) = vb[i];
      *(uint4*)(&sBh[r * 40 + c8]) = vc[i];
      *(uint4*)(&sBl[r * 40 + c8]) = vd[i];
    }
    __syncthreads();

    short8 fah[4], fal[4], fbh[4], fbl[4];
#pragma unroll
    for (int t = 0; t < 4; ++t) {
      int ra = (wm * 64 + t * 16 + col) * 40 + quad * 8;
      fah[t] = *(const short8*)(&sAh[ra]);
      fal[t] = *(const short8*)(&sAl[ra]);
      int rb = (wn * 64 + t * 16 + col) * 40 + quad * 8;
      fbh[t] = *(const short8*)(&sBh[rb]);
      fbl[t] = *(const short8*)(&sBl[rb]);
    }
#pragma unroll
    for (int tm = 0; tm < 4; ++tm)
#pragma unroll
      for (int tn = 0; tn < 4; ++tn) {
        acc[tm][tn] = __builtin_amdgcn_mfma_f32_16x16x32_bf16(fah[tm], fbh[tn], acc[tm][tn], 0, 0, 0);
        acc[tm][tn] = __builtin_amdgcn_mfma_f32_16x16x32_bf16(fah[tm], fbl[tn], acc[tm][tn], 0, 0, 0);
        acc[tm][tn] = __builtin_amdgcn_mfma_f32_16x16x32_bf16(fal[tm], fbh[tn], acc[tm][tn], 0, 0, 0);
      }
  }

  const int m_base = bm * 128 + wm * 64;
  const int n_base = bn * 128 + wn * 64;

  if (mode == 0) {
#pragma unroll
    for (int tm = 0; tm < 4; ++tm)
#pragma unroll
      for (int tn = 0; tn < 4; ++tn) {
        int gn = n_base + tn * 16 + col;
        float b = bias[gn];
#pragma unroll
        for (int rr = 0; rr < 4; ++rr) {
          int gm = m_base + tm * 16 + quad * 4 + rr;
          Cout[(size_t)gm * N + gn] = acc[tm][tn][rr] + b;
        }
      }
  } else {
    int reg = bn / 6;  // 0:Q 1:K 2:V  (uniform per block)
#pragma unroll
    for (int tm = 0; tm < 4; ++tm)
#pragma unroll
      for (int tn = 0; tn < 4; ++tn) {
        int el = (bn % 6) * 128 + wn * 64 + tn * 16 + col;  // 0..767
        int hh = el >> 6, dd = el & 63;
#pragma unroll
        for (int rr = 0; rr < 4; ++rr) {
          int gm = m_base + tm * 16 + quad * 4 + rr;
          float v = acc[tm][tn][rr];
          if (reg == 0) {
            v *= QSCALE;
            ushort hi = f2bf(v);
            size_t idx = ((size_t)hh * SEQ + gm) * HD + dd;  // Q unswizzled
            Qh[idx] = hi;
            Ql[idx] = f2bf(v - bf2f(hi));
          } else if (reg == 1) {
            // K swizzled: 8 chunks of 8 dims; chunk' = chunk ^ (key&7)
            ushort hi = f2bf(v);
            int pc = ((dd >> 3) ^ (gm & 7)) & 7;
            size_t idx = ((size_t)hh * SEQ + gm) * HD + pc * 8 + (dd & 7);
            Kh[idx] = hi;
            Kl[idx] = f2bf(v - bf2f(hi));
          } else {
            // Vt swizzled within each 128-key window: 16 chunks of 8 keys;
            // chunk' = chunk ^ (dim&15)
            int pc = (((gm >> 3) & 15) ^ (dd & 15)) & 15;
            size_t idx = ((size_t)hh * HD + dd) * SEQ + (gm & ~127) + pc * 8 + (gm & 7);
            Vt[idx] = f2bf(v);
          }
        }
      }
  }
}

// Flash attention, R4: K/V staged via global_load_lds DMA (zero VGPR -> no
// spill; R3's register prefetch spilled 930 MB to scratch). LDS image is
// XOR-chunk swizzled (baked into the global layout) so unpadded b128 fragment
// reads sit at the 8-phase floor. m97-style 2-barrier loop; LDS 64KB -> 2
// blocks/CU.
__global__ __launch_bounds__(256, 2) void attn_k(
    const ushort* __restrict__ Qh, const ushort* __restrict__ Ql,
    const ushort* __restrict__ Kh, const ushort* __restrict__ Kl,
    const ushort* __restrict__ Vt,
    ushort* __restrict__ Ch, ushort* __restrict__ Cl) {
  __shared__ ushort sKh[128 * 64];   // [key][chunk^key&7][8]
  __shared__ ushort sKl[128 * 64];
  __shared__ ushort sVt[64 * 128];   // [dim][chunk^dim&15][8]
  __shared__ ushort sP[4][16 * 128]; // per-wave, [row][chunk^row][8]

  const int tid = threadIdx.x, lane = tid & 63, w = tid >> 6;
  const int col = lane & 15, quad = lane >> 4;
  const int h = blockIdx.y;
  const int q0 = blockIdx.x * 64 + w * 16;

  const ushort* qh_base = Qh + ((size_t)h * SEQ + q0 + col) * HD;
  const ushort* ql_base = Ql + ((size_t)h * SEQ + q0 + col) * HD;
  short8 fqh[2], fql[2];
#pragma unroll
  for (int ks = 0; ks < 2; ++ks) {
    fqh[ks] = *(const short8*)(qh_base + ks * 32 + quad * 8);
    fql[ks] = *(const short8*)(ql_base + ks * 32 + quad * 8);
  }

  float m2[4], ell[4];
  f32x4 o[4];
  const f32x4 zz = {0.f, 0.f, 0.f, 0.f};
#pragma unroll
  for (int i = 0; i < 4; ++i) { m2[i] = -1e30f; ell[i] = 0.f; o[i] = zz; }

  const ushort* khg = Kh + (size_t)h * SEQ * HD;  // swizzled [key][64]
  const ushort* klg = Kl + (size_t)h * SEQ * HD;
  const ushort* vtg = Vt + (size_t)h * HD * SEQ;  // swizzled [dim][SEQ]
  ushort* pw = &sP[w][0];

  for (int kb = 0; kb < SEQ; kb += 128) {
    __syncthreads();  // all waves done reading previous tile
    // ---- DMA staging: 48 chunks of 1KB, 12 per wave, lane-ordered ----
#pragma unroll
    for (int i = 0; i < 12; ++i) {
      int idx = w * 12 + i;
      const ushort* g;
      ushort* l;
      if (idx < 16) {            // sKh: 8 K-rows (128B each) per chunk
        g = khg + (size_t)(kb + idx * 8 + (lane >> 3)) * 64 + (lane & 7) * 8;
        l = sKh + idx * 512;
      } else if (idx < 32) {
        int j = idx - 16;
        g = klg + (size_t)(kb + j * 8 + (lane >> 3)) * 64 + (lane & 7) * 8;
        l = sKl + j * 512;
      } else {                   // sVt: 4 V-rows (256B each) per chunk
        int j = idx - 32;
        g = vtg + (size_t)(j * 4 + (lane >> 4)) * SEQ + kb + (lane & 15) * 8;
        l = sVt + j * 512;
      }
      __builtin_amdgcn_global_load_lds(
          (const GLOBAL_AS unsigned int*)g, (LDS_AS unsigned int*)l, 16, 0, 0);
    }
    asm volatile("s_waitcnt vmcnt(0)" ::: "memory");
    __syncthreads();

    // ---- scores for 128 keys: 8 tiles of 16, 3-term split MFMA ----
    f32x4 s[8];
#pragma unroll
    for (int tn = 0; tn < 8; ++tn) {
      f32x4 a = zz;
#pragma unroll
      for (int ks = 0; ks < 2; ++ks) {
#pragma unroll
        for (int half = 0; half < 1; ++half) {}
        int pc0 = ((4 * ks + quad) ^ (col & 7)) & 7;
        const int rowb = (tn * 16 + col) * 64;
        short8 fkh = *(const short8*)(&sKh[rowb + pc0 * 8]);
        short8 fkl = *(const short8*)(&sKl[rowb + pc0 * 8]);
        a = __builtin_amdgcn_mfma_f32_16x16x32_bf16(fqh[ks], fkh, a, 0, 0, 0);
        a = __builtin_amdgcn_mfma_f32_16x16x32_bf16(fqh[ks], fkl, a, 0, 0, 0);
        a = __builtin_amdgcn_mfma_f32_16x16x32_bf16(fql[ks], fkh, a, 0, 0, 0);
      }
      s[tn] = a;
    }

    // ---- online softmax (exp2 domain) ----
    float vm[4];
#pragma unroll
    for (int rr = 0; rr < 4; ++rr) {
      float a0 = fmaxf(fmaxf(s[0][rr], s[1][rr]), fmaxf(s[2][rr], s[3][rr]));
      float a1 = fmaxf(fmaxf(s[4][rr], s[5][rr]), fmaxf(s[6][rr], s[7][rr]));
      vm[rr] = fmaxf(a0, a1);
    }
#pragma unroll
    for (int mk = 1; mk < 16; mk <<= 1)
#pragma unroll
      for (int rr = 0; rr < 4; ++rr) vm[rr] = fmaxf(vm[rr], __shfl_xor(vm[rr], mk, 64));

    float mn[4], alpha[4];
#pragma unroll
    for (int rr = 0; rr < 4; ++rr) {
      mn[rr] = fmaxf(m2[rr], vm[rr]);
      alpha[rr] = exp2f(m2[rr] - mn[rr]);
      m2[rr] = mn[rr];
      ell[rr] *= alpha[rr];
    }
#pragma unroll
    for (int td = 0; td < 4; ++td)
#pragma unroll
      for (int rr = 0; rr < 4; ++rr) o[td][rr] *= alpha[rr];

    float rs[4] = {0.f, 0.f, 0.f, 0.f};
#pragma unroll
    for (int tn = 0; tn < 8; ++tn)
#pragma unroll
      for (int rr = 0; rr < 4; ++rr) {
        float p = exp2f(s[tn][rr] - mn[rr]);
        rs[rr] += p;
        int row = quad * 4 + rr;
        int pc = ((2 * tn + (col >> 3)) ^ row) & 15;
        pw[row * 128 + pc * 8 + (col & 7)] = f2bf(p);
      }
#pragma unroll
    for (int mk = 1; mk < 16; mk <<= 1)
#pragma unroll
      for (int rr = 0; rr < 4; ++rr) rs[rr] += __shfl_xor(rs[rr], mk, 64);
#pragma unroll
    for (int rr = 0; rr < 4; ++rr) ell[rr] += rs[rr];

    // drain this wave's P writes before reading back (wave-private region)
    asm volatile("s_waitcnt lgkmcnt(0)" ::: "memory");

    short8 fp[4];
#pragma unroll
    for (int ks = 0; ks < 4; ++ks) {
      int pc = ((4 * ks + quad) ^ col) & 15;
      fp[ks] = *(const short8*)(pw + col * 128 + pc * 8);
    }

#pragma unroll
    for (int td = 0; td < 4; ++td) {
#pragma unroll
      for (int ks = 0; ks < 4; ++ks) {
        int pc = ((4 * ks + quad) ^ col) & 15;
        short8 fv = *(const short8*)(&sVt[(td * 16 + col) * 128 + pc * 8]);
        o[td] = __builtin_amdgcn_mfma_f32_16x16x32_bf16(fp[ks], fv, o[td], 0, 0, 0);
      }
    }
  }

  // epilogue: normalize, split to bf16 hi/lo ctx [4096][768]
#pragma unroll
  for (int td = 0; td < 4; ++td)
#pragma unroll
    for (int rr = 0; rr < 4; ++rr) {
      float v = o[td][rr] / ell[rr];
      int l = q0 + quad * 4 + rr;
      int d = h * 64 + td * 16 + col;
      ushort hi = f2bf(v);
      size_t idx = (size_t)l * EMB + d;
      Ch[idx] = hi;
      Cl[idx] = f2bf(v - bf2f(hi));
    }
}

extern "C" void kernel_launch(void* const* d_in, const int* in_sizes, int n_in,
                              void* d_out, int out_size, void* d_ws, size_t ws_size,
                              hipStream_t stream) {
  const float* x = (const float*)d_in[0];       // [4096][768]
  const float* qkv_w = (const float*)d_in[1];   // [2304][768]
  const float* out_w = (const float*)d_in[2];   // [768][768]
  const float* out_b = (const float*)d_in[3];   // [768]
  float* out = (float*)d_out;                   // [4096][768]

  char* p = (char*)d_ws;
  auto carve = [&](size_t bytes) {
    char* q = p;
    p += (bytes + 255) & ~(size_t)255;
    return q;
  };
  const size_t NX = (size_t)SEQ * EMB;       // 3,145,728
  const size_t NQW = (size_t)3 * EMB * EMB;  // 1,769,472
  const size_t NOW = (size_t)EMB * EMB;      // 589,824
  const size_t NQKV = (size_t)NH * SEQ * HD; // 3,145,728

  ushort* xh = (ushort*)carve(NX * 2);
  ushort* xl = (ushort*)carve(NX * 2);
  ushort* qwh = (ushort*)carve(NQW * 2);
  ushort* qwl = (ushort*)carve(NQW * 2);
  ushort* owh = (ushort*)carve(NOW * 2);
  ushort* owl = (ushort*)carve(NOW * 2);
  ushort* Qh = (ushort*)carve(NQKV * 2);
  ushort* Ql = (ushort*)carve(NQKV * 2);
  ushort* Kh = (ushort*)carve(NQKV * 2);
  ushort* Kl = (ushort*)carve(NQKV * 2);
  ushort* Vt = (ushort*)carve(NQKV * 2);
  ushort* Ch = (ushort*)carve(NX * 2);
  ushort* Cl = (ushort*)carve(NX * 2);

  split_k<<<dim3((int)(NX / 256)), 256, 0, stream>>>(x, xh, xl, (int)NX);
  split_k<<<dim3((int)(NQW / 256)), 256, 0, stream>>>(qkv_w, qwh, qwl, (int)NQW);
  split_k<<<dim3((int)(NOW / 256)), 256, 0, stream>>>(out_w, owh, owl, (int)NOW);

  // QKV: M=4096, N=2304, K=768 -> scatter epilogue (K/V swizzled)
  gemm_bt_split<<<dim3(32, 18), 256, 0, stream>>>(
      xh, xl, qwh, qwl, SEQ, 3 * EMB, EMB, 1,
      nullptr, nullptr, Qh, Ql, Kh, Kl, Vt);

  attn_k<<<dim3(SEQ / 64, NH), 256, 0, stream>>>(Qh, Ql, Kh, Kl, Vt, Ch, Cl);

  // out proj: M=4096, N=768, K=768, + bias -> d_out
  gemm_bt_split<<<dim3(32, 6), 256, 0, stream>>>(
      Ch, Cl, owh, owl, SEQ, EMB, EMB, 0,
      out, out_b, nullptr, nullptr, nullptr, nullptr, nullptr);
}

// Round 5
// 400.003 us; speedup vs baseline: 2.1808x; 1.4172x over previous
//
#include <hip/hip_runtime.h>

typedef __attribute__((ext_vector_type(8))) short short8;
typedef __attribute__((ext_vector_type(4))) float f32x4;

#define EMB 768
#define SEQ 4096
#define NH 12
#define HD 64
// 8 * log2(e): folds the score scale AND the exp->exp2 conversion into Q
#define QSCALE 11.541560327111707f

#define GLOBAL_AS __attribute__((address_space(1)))
#define LDS_AS __attribute__((address_space(3)))

__device__ inline ushort f2bf(float v) {
  union { float f; unsigned int u; } x; x.f = v;
  unsigned int r = x.u + 0x7fffu + ((x.u >> 16) & 1u);
  return (ushort)(r >> 16);
}
__device__ inline float bf2f(ushort u) {
  union { float f; unsigned int u32; } x; x.u32 = ((unsigned int)u) << 16;
  return x.f;
}

__global__ void split_k(const float* __restrict__ src, ushort* __restrict__ hi,
                        ushort* __restrict__ lo, int n) {
  int i = blockIdx.x * blockDim.x + threadIdx.x;
  if (i < n) {
    float v = src[i];
    ushort h = f2bf(v);
    hi[i] = h;
    lo[i] = f2bf(v - bf2f(h));
  }
}

// C[m,n] = sum_k A[m,k]*B[n,k] (both K-contiguous), fp32-accurate via 3-term
// bf16 split MFMA. R5: staging via global_load_lds DMA (m97 2-barrier loop;
// R4 version was latency-bound on VGPR staging loads: MfmaUtil 6.5%).
// mode 0: C += bias -> Cout fp32. mode 1: scatter QKV; V goes through an LDS
// transpose so the SEQ-strided Vt layout gets coalesced 16B stores (R4: 287MB
// WRITE_SIZE from 2B scatter, ~32x amplification).
__global__ __launch_bounds__(256) void gemm_bt_split(
    const ushort* __restrict__ Ah, const ushort* __restrict__ Al,
    const ushort* __restrict__ Bh, const ushort* __restrict__ Bl,
    int M, int N, int K, int mode,
    float* __restrict__ Cout, const float* __restrict__ bias,
    ushort* __restrict__ Qh, ushort* __restrict__ Ql,
    ushort* __restrict__ Kh, ushort* __restrict__ Kl,
    ushort* __restrict__ Vt) {
  // 4 x 8KB staging tiles [128 rows][32 k], unpadded (DMA is lane-ordered).
  // b128 fragment reads: addr = row*64B + quad*16B -> uniform 8 lanes/bank
  // (structural floor, conflict-free). Reused as 32KB V-transpose buffer.
  __shared__ ushort smem[4 * 128 * 32];
  ushort* sAh = smem;
  ushort* sAl = smem + 4096;
  ushort* sBh = smem + 8192;
  ushort* sBl = smem + 12288;

  const int tid = threadIdx.x;
  const int lane = tid & 63;
  const int w = tid >> 6;
  const int wm = w >> 1, wn = w & 1;
  const int col = lane & 15, quad = lane >> 4;
  const int bm = blockIdx.x, bn = blockIdx.y;

  // DMA: wave w stages matrix w; chunk i (0..7) = rows [i*16, i*16+16) of the
  // tile; lane deposits 16B at lds + i*1024 + lane*16 <- global row i*16+(lane>>2),
  // kcol (lane&3)*8.
  const ushort* gsrc = (w == 0)   ? Ah + (size_t)bm * 128 * K
                       : (w == 1) ? Al + (size_t)bm * 128 * K
                       : (w == 2) ? Bh + (size_t)bn * 128 * K
                                  : Bl + (size_t)bn * 128 * K;
  ushort* lbase = (w == 0) ? sAh : (w == 1) ? sAl : (w == 2) ? sBh : sBl;
  const ushort* g0 = gsrc + (size_t)(lane >> 2) * K + (lane & 3) * 8;

  f32x4 acc[4][4];
  const f32x4 zz = {0.f, 0.f, 0.f, 0.f};
#pragma unroll
  for (int i = 0; i < 4; ++i)
#pragma unroll
    for (int j = 0; j < 4; ++j) acc[i][j] = zz;

  for (int kt = 0; kt < K; kt += 32) {
    __syncthreads();  // all waves done reading previous tile
#pragma unroll
    for (int i = 0; i < 8; ++i) {
      __builtin_amdgcn_global_load_lds(
          (const GLOBAL_AS unsigned int*)(g0 + (size_t)i * 16 * K + kt),
          (LDS_AS unsigned int*)(lbase + i * 512), 16, 0, 0);
    }
    asm volatile("s_waitcnt vmcnt(0)" ::: "memory");
    __syncthreads();

    short8 fah[4], fal[4], fbh[4], fbl[4];
#pragma unroll
    for (int t = 0; t < 4; ++t) {
      int ra = (wm * 64 + t * 16 + col) * 32 + quad * 8;
      fah[t] = *(const short8*)(&sAh[ra]);
      fal[t] = *(const short8*)(&sAl[ra]);
      int rb = (wn * 64 + t * 16 + col) * 32 + quad * 8;
      fbh[t] = *(const short8*)(&sBh[rb]);
      fbl[t] = *(const short8*)(&sBl[rb]);
    }
#pragma unroll
    for (int tm = 0; tm < 4; ++tm)
#pragma unroll
      for (int tn = 0; tn < 4; ++tn) {
        acc[tm][tn] = __builtin_amdgcn_mfma_f32_16x16x32_bf16(fah[tm], fbh[tn], acc[tm][tn], 0, 0, 0);
        acc[tm][tn] = __builtin_amdgcn_mfma_f32_16x16x32_bf16(fah[tm], fbl[tn], acc[tm][tn], 0, 0, 0);
        acc[tm][tn] = __builtin_amdgcn_mfma_f32_16x16x32_bf16(fal[tm], fbh[tn], acc[tm][tn], 0, 0, 0);
      }
  }

  const int m_base = bm * 128 + wm * 64;
  const int n_base = bn * 128 + wn * 64;

  if (mode == 0) {
#pragma unroll
    for (int tm = 0; tm < 4; ++tm)
#pragma unroll
      for (int tn = 0; tn < 4; ++tn) {
        int gn = n_base + tn * 16 + col;
        float b = bias[gn];
#pragma unroll
        for (int rr = 0; rr < 4; ++rr) {
          int gm = m_base + tm * 16 + quad * 4 + rr;
          Cout[(size_t)gm * N + gn] = acc[tm][tn][rr] + b;
        }
      }
  } else {
    int reg = bn / 6;  // 0:Q 1:K 2:V (uniform per block)
    if (reg < 2) {
#pragma unroll
      for (int tm = 0; tm < 4; ++tm)
#pragma unroll
        for (int tn = 0; tn < 4; ++tn) {
          int el = (bn % 6) * 128 + wn * 64 + tn * 16 + col;  // 0..767
          int hh = el >> 6, dd = el & 63;
#pragma unroll
          for (int rr = 0; rr < 4; ++rr) {
            int gm = m_base + tm * 16 + quad * 4 + rr;
            float v = acc[tm][tn][rr];
            if (reg == 0) {
              v *= QSCALE;
              ushort hi = f2bf(v);
              size_t idx = ((size_t)hh * SEQ + gm) * HD + dd;  // Q unswizzled
              Qh[idx] = hi;
              Ql[idx] = f2bf(v - bf2f(hi));
            } else {
              // K swizzled: chunk' = chunk ^ (key&7) for attn's DMA image
              ushort hi = f2bf(v);
              int pc = ((dd >> 3) ^ (gm & 7)) & 7;
              size_t idx = ((size_t)hh * SEQ + gm) * HD + pc * 8 + (dd & 7);
              Kh[idx] = hi;
              Kl[idx] = f2bf(v - bf2f(hi));
            }
          }
        }
    } else {
      // ---- V: LDS transpose -> coalesced swizzled stores ----
      // vt_tile[el][seq], el=tile dim 0..127, seq=tile key 0..127; logical
      // chunk c=seq>>3 stored at slot c^(el&15). Global Vt layout stores
      // logical chunk c at position c^(dd&15); dd&15 == el&15, so LDS slot j
      // copies linearly to global chunk j.
      __syncthreads();  // block-uniform path: safe barrier; staging reads done
      ushort* vt_tile = smem;  // 128*128 ushort = 32KB
#pragma unroll
      for (int tm = 0; tm < 4; ++tm)
#pragma unroll
        for (int tn = 0; tn < 4; ++tn) {
          int el = wn * 64 + tn * 16 + col;
#pragma unroll
          for (int rr = 0; rr < 4; ++rr) {
            int seq = wm * 64 + tm * 16 + quad * 4 + rr;
            int cc = ((seq >> 3) ^ (el & 15)) & 15;
            vt_tile[el * 128 + cc * 8 + (seq & 7)] = f2bf(acc[tm][tn][rr]);
          }
        }
      __syncthreads();
      // copy 128 rows x 256B to global; thread t: row tid>>1, 8 chunks,
      // chunk index rotated by el to avoid LDS read bank conflicts
      int el = tid >> 1;
      int elg = (bn % 6) * 128 + el;
      int hh = elg >> 6, dd = elg & 63;
      ushort* grow = Vt + (size_t)(hh * HD + dd) * SEQ + bm * 128;
#pragma unroll
      for (int i = 0; i < 8; ++i) {
        int c = ((tid & 1) * 8 + i + el) & 15;
        *(uint4*)(grow + c * 8) = *(const uint4*)(&vt_tile[el * 128 + c * 8]);
      }
    }
  }
}

// Flash attention (unchanged from R4): K/V staged via global_load_lds DMA with
// XOR-chunk-swizzled global layout -> 0 bank conflicts. LDS 64KB -> 2 blocks/CU.
__global__ __launch_bounds__(256, 2) void attn_k(
    const ushort* __restrict__ Qh, const ushort* __restrict__ Ql,
    const ushort* __restrict__ Kh, const ushort* __restrict__ Kl,
    const ushort* __restrict__ Vt,
    ushort* __restrict__ Ch, ushort* __restrict__ Cl) {
  __shared__ ushort sKh[128 * 64];   // [key][chunk^key&7][8]
  __shared__ ushort sKl[128 * 64];
  __shared__ ushort sVt[64 * 128];   // [dim][chunk^dim&15][8]
  __shared__ ushort sP[4][16 * 128]; // per-wave, [row][chunk^row][8]

  const int tid = threadIdx.x, lane = tid & 63, w = tid >> 6;
  const int col = lane & 15, quad = lane >> 4;
  const int h = blockIdx.y;
  const int q0 = blockIdx.x * 64 + w * 16;

  const ushort* qh_base = Qh + ((size_t)h * SEQ + q0 + col) * HD;
  const ushort* ql_base = Ql + ((size_t)h * SEQ + q0 + col) * HD;
  short8 fqh[2], fql[2];
#pragma unroll
  for (int ks = 0; ks < 2; ++ks) {
    fqh[ks] = *(const short8*)(qh_base + ks * 32 + quad * 8);
    fql[ks] = *(const short8*)(ql_base + ks * 32 + quad * 8);
  }

  float m2[4], ell[4];
  f32x4 o[4];
  const f32x4 zz = {0.f, 0.f, 0.f, 0.f};
#pragma unroll
  for (int i = 0; i < 4; ++i) { m2[i] = -1e30f; ell[i] = 0.f; o[i] = zz; }

  const ushort* khg = Kh + (size_t)h * SEQ * HD;  // swizzled [key][64]
  const ushort* klg = Kl + (size_t)h * SEQ * HD;
  const ushort* vtg = Vt + (size_t)h * HD * SEQ;  // swizzled [dim][SEQ]
  ushort* pw = &sP[w][0];

  for (int kb = 0; kb < SEQ; kb += 128) {
    __syncthreads();  // all waves done reading previous tile
#pragma unroll
    for (int i = 0; i < 12; ++i) {
      int idx = w * 12 + i;
      const ushort* g;
      ushort* l;
      if (idx < 16) {            // sKh: 8 K-rows (128B each) per chunk
        g = khg + (size_t)(kb + idx * 8 + (lane >> 3)) * 64 + (lane & 7) * 8;
        l = sKh + idx * 512;
      } else if (idx < 32) {
        int j = idx - 16;
        g = klg + (size_t)(kb + j * 8 + (lane >> 3)) * 64 + (lane & 7) * 8;
        l = sKl + j * 512;
      } else {                   // sVt: 4 V-rows (256B each) per chunk
        int j = idx - 32;
        g = vtg + (size_t)(j * 4 + (lane >> 4)) * SEQ + kb + (lane & 15) * 8;
        l = sVt + j * 512;
      }
      __builtin_amdgcn_global_load_lds(
          (const GLOBAL_AS unsigned int*)g, (LDS_AS unsigned int*)l, 16, 0, 0);
    }
    asm volatile("s_waitcnt vmcnt(0)" ::: "memory");
    __syncthreads();

    // ---- scores for 128 keys: 8 tiles of 16, 3-term split MFMA ----
    f32x4 s[8];
#pragma unroll
    for (int tn = 0; tn < 8; ++tn) {
      f32x4 a = zz;
#pragma unroll
      for (int ks = 0; ks < 2; ++ks) {
        int pc0 = ((4 * ks + quad) ^ (col & 7)) & 7;
        const int rowb = (tn * 16 + col) * 64;
        short8 fkh = *(const short8*)(&sKh[rowb + pc0 * 8]);
        short8 fkl = *(const short8*)(&sKl[rowb + pc0 * 8]);
        a = __builtin_amdgcn_mfma_f32_16x16x32_bf16(fqh[ks], fkh, a, 0, 0, 0);
        a = __builtin_amdgcn_mfma_f32_16x16x32_bf16(fqh[ks], fkl, a, 0, 0, 0);
        a = __builtin_amdgcn_mfma_f32_16x16x32_bf16(fql[ks], fkh, a, 0, 0, 0);
      }
      s[tn] = a;
    }

    // ---- online softmax (exp2 domain) ----
    float vm[4];
#pragma unroll
    for (int rr = 0; rr < 4; ++rr) {
      float a0 = fmaxf(fmaxf(s[0][rr], s[1][rr]), fmaxf(s[2][rr], s[3][rr]));
      float a1 = fmaxf(fmaxf(s[4][rr], s[5][rr]), fmaxf(s[6][rr], s[7][rr]));
      vm[rr] = fmaxf(a0, a1);
    }
#pragma unroll
    for (int mk = 1; mk < 16; mk <<= 1)
#pragma unroll
      for (int rr = 0; rr < 4; ++rr) vm[rr] = fmaxf(vm[rr], __shfl_xor(vm[rr], mk, 64));

    float mn[4], alpha[4];
#pragma unroll
    for (int rr = 0; rr < 4; ++rr) {
      mn[rr] = fmaxf(m2[rr], vm[rr]);
      alpha[rr] = exp2f(m2[rr] - mn[rr]);
      m2[rr] = mn[rr];
      ell[rr] *= alpha[rr];
    }
#pragma unroll
    for (int td = 0; td < 4; ++td)
#pragma unroll
      for (int rr = 0; rr < 4; ++rr) o[td][rr] *= alpha[rr];

    float rs[4] = {0.f, 0.f, 0.f, 0.f};
#pragma unroll
    for (int tn = 0; tn < 8; ++tn)
#pragma unroll
      for (int rr = 0; rr < 4; ++rr) {
        float p = exp2f(s[tn][rr] - mn[rr]);
        rs[rr] += p;
        int row = quad * 4 + rr;
        int pc = ((2 * tn + (col >> 3)) ^ row) & 15;
        pw[row * 128 + pc * 8 + (col & 7)] = f2bf(p);
      }
#pragma unroll
    for (int mk = 1; mk < 16; mk <<= 1)
#pragma unroll
      for (int rr = 0; rr < 4; ++rr) rs[rr] += __shfl_xor(rs[rr], mk, 64);
#pragma unroll
    for (int rr = 0; rr < 4; ++rr) ell[rr] += rs[rr];

    // drain this wave's P writes before reading back (wave-private region)
    asm volatile("s_waitcnt lgkmcnt(0)" ::: "memory");

    short8 fp[4];
#pragma unroll
    for (int ks = 0; ks < 4; ++ks) {
      int pc = ((4 * ks + quad) ^ col) & 15;
      fp[ks] = *(const short8*)(pw + col * 128 + pc * 8);
    }

#pragma unroll
    for (int td = 0; td < 4; ++td) {
#pragma unroll
      for (int ks = 0; ks < 4; ++ks) {
        int pc = ((4 * ks + quad) ^ col) & 15;
        short8 fv = *(const short8*)(&sVt[(td * 16 + col) * 128 + pc * 8]);
        o[td] = __builtin_amdgcn_mfma_f32_16x16x32_bf16(fp[ks], fv, o[td], 0, 0, 0);
      }
    }
  }

  // epilogue: normalize, split to bf16 hi/lo ctx [4096][768]
#pragma unroll
  for (int td = 0; td < 4; ++td)
#pragma unroll
    for (int rr = 0; rr < 4; ++rr) {
      float v = o[td][rr] / ell[rr];
      int l = q0 + quad * 4 + rr;
      int d = h * 64 + td * 16 + col;
      ushort hi = f2bf(v);
      size_t idx = (size_t)l * EMB + d;
      Ch[idx] = hi;
      Cl[idx] = f2bf(v - bf2f(hi));
    }
}

extern "C" void kernel_launch(void* const* d_in, const int* in_sizes, int n_in,
                              void* d_out, int out_size, void* d_ws, size_t ws_size,
                              hipStream_t stream) {
  const float* x = (const float*)d_in[0];       // [4096][768]
  const float* qkv_w = (const float*)d_in[1];   // [2304][768]
  const float* out_w = (const float*)d_in[2];   // [768][768]
  const float* out_b = (const float*)d_in[3];   // [768]
  float* out = (float*)d_out;                   // [4096][768]

  char* p = (char*)d_ws;
  auto carve = [&](size_t bytes) {
    char* q = p;
    p += (bytes + 255) & ~(size_t)255;
    return q;
  };
  const size_t NX = (size_t)SEQ * EMB;       // 3,145,728
  const size_t NQW = (size_t)3 * EMB * EMB;  // 1,769,472
  const size_t NOW = (size_t)EMB * EMB;      // 589,824
  const size_t NQKV = (size_t)NH * SEQ * HD; // 3,145,728

  ushort* xh = (ushort*)carve(NX * 2);
  ushort* xl = (ushort*)carve(NX * 2);
  ushort* qwh = (ushort*)carve(NQW * 2);
  ushort* qwl = (ushort*)carve(NQW * 2);
  ushort* owh = (ushort*)carve(NOW * 2);
  ushort* owl = (ushort*)carve(NOW * 2);
  ushort* Qh = (ushort*)carve(NQKV * 2);
  ushort* Ql = (ushort*)carve(NQKV * 2);
  ushort* Kh = (ushort*)carve(NQKV * 2);
  ushort* Kl = (ushort*)carve(NQKV * 2);
  ushort* Vt = (ushort*)carve(NQKV * 2);
  ushort* Ch = (ushort*)carve(NX * 2);
  ushort* Cl = (ushort*)carve(NX * 2);

  split_k<<<dim3((int)(NX / 256)), 256, 0, stream>>>(x, xh, xl, (int)NX);
  split_k<<<dim3((int)(NQW / 256)), 256, 0, stream>>>(qkv_w, qwh, qwl, (int)NQW);
  split_k<<<dim3((int)(NOW / 256)), 256, 0, stream>>>(out_w, owh, owl, (int)NOW);

  // QKV: M=4096, N=2304, K=768 -> scatter epilogue (K/V swizzled)
  gemm_bt_split<<<dim3(32, 18), 256, 0, stream>>>(
      xh, xl, qwh, qwl, SEQ, 3 * EMB, EMB, 1,
      nullptr, nullptr, Qh, Ql, Kh, Kl, Vt);

  attn_k<<<dim3(SEQ / 64, NH), 256, 0, stream>>>(Qh, Ql, Kh, Kl, Vt, Ch, Cl);

  // out proj: M=4096, N=768, K=768, + bias -> d_out
  gemm_bt_split<<<dim3(32, 6), 256, 0, stream>>>(
      Ch, Cl, owh, owl, SEQ, EMB, EMB, 0,
      out, out_b, nullptr, nullptr, nullptr, nullptr, nullptr);
}